// Round 1
// baseline (463.184 us; speedup 1.0000x reference)
//
#include <hip/hip_runtime.h>

#define HIDDEN 2048
#define NH 16
#define NKV 4
#define HD 128
#define Bb 2
#define Ss 2048
#define TOK 4096           // Bb*Ss
#define KVD 512            // NKV*HD
#define QSCALE 0.08838834764831845f   // 1/sqrt(128)

typedef short short8 __attribute__((ext_vector_type(8)));
typedef float f32x4 __attribute__((ext_vector_type(4)));

#define AS1 __attribute__((address_space(1)))
#define AS3 __attribute__((address_space(3)))

__device__ __forceinline__ float bf2f(unsigned short u){
  union { unsigned int i; float f; } x; x.i = ((unsigned int)u) << 16; return x.f;
}
__device__ __forceinline__ unsigned short f2bf(float f){
  union { float f; unsigned int i; } x; x.f = f;
  unsigned int r = x.i + 0x7FFFu + ((x.i >> 16) & 1u);   // RNE
  return (unsigned short)(r >> 16);
}
__device__ __forceinline__ void gld_lds16(const void* g, void* l){
  __builtin_amdgcn_global_load_lds((const AS1 void*)g, (AS3 void*)l, 16, 0, 0);
}

// ---------------- fp32 -> bf16 conversion (vectorized) ----------------
__global__ void cvt_kernel(const float* __restrict__ in, unsigned short* __restrict__ out, int n4){
  int i = blockIdx.x * blockDim.x + threadIdx.x;
  if (i >= n4) return;
  float4 v = reinterpret_cast<const float4*>(in)[i];
  ushort4 o;
  o.x = f2bf(v.x); o.y = f2bf(v.y); o.z = f2bf(v.z); o.w = f2bf(v.w);
  reinterpret_cast<ushort4*>(out)[i] = o;
}

// ---------------- NT GEMM: C[M,N] = A[M,K] * B[N,K]^T (+bias) ----------------
// 128x128 tile, BK=32, 4 waves (2x2), each wave 64x64 via 4x4 16x16x32 MFMA frags.
__global__ __launch_bounds__(256) void gemm_nt(
    const unsigned short* __restrict__ A,
    const unsigned short* __restrict__ Bw,
    const float* __restrict__ bias,        // may be null
    unsigned short* __restrict__ Cb,       // bf16 out (if Cf==null)
    float* __restrict__ Cf,                // f32 out (if non-null)
    int M, int N, int K)
{
  __shared__ unsigned short Alds[128*32];
  __shared__ unsigned short Blds[128*32];
  const int tid  = threadIdx.x;
  const int lane = tid & 63;
  const int wr = (tid >> 7) & 1;
  const int wc = (tid >> 6) & 1;
  const int row0 = blockIdx.x * 128;
  const int col0 = blockIdx.y * 128;

  const f32x4 vzero = {0.f, 0.f, 0.f, 0.f};
  f32x4 acc[4][4];
#pragma unroll
  for (int m = 0; m < 4; m++)
#pragma unroll
    for (int n = 0; n < 4; n++) acc[m][n] = vzero;

  // staging chunks: 512 x 16B per tile; chunk c -> row c>>2, k-offset (c&3)*8
  const int c0 = tid, c1 = tid + 256;
  const int ra0 = c0 >> 2, ka0 = (c0 & 3) * 8;
  const int ra1 = c1 >> 2, ka1 = (c1 & 3) * 8;

  const int fr  = lane & 15;
  const int fk8 = (lane >> 4) * 8;

  for (int kt = 0; kt < K; kt += 32){
    gld_lds16(A  + (size_t)(row0 + ra0) * K + kt + ka0, &Alds[c0 * 8]);
    gld_lds16(A  + (size_t)(row0 + ra1) * K + kt + ka1, &Alds[c1 * 8]);
    gld_lds16(Bw + (size_t)(col0 + ra0) * K + kt + ka0, &Blds[c0 * 8]);
    gld_lds16(Bw + (size_t)(col0 + ra1) * K + kt + ka1, &Blds[c1 * 8]);
    __syncthreads();

    short8 af[4], bf[4];
#pragma unroll
    for (int m = 0; m < 4; m++) af[m] = *(const short8*)&Alds[(wr*64 + m*16 + fr)*32 + fk8];
#pragma unroll
    for (int n = 0; n < 4; n++) bf[n] = *(const short8*)&Blds[(wc*64 + n*16 + fr)*32 + fk8];
#pragma unroll
    for (int m = 0; m < 4; m++)
#pragma unroll
      for (int n = 0; n < 4; n++)
        acc[m][n] = __builtin_amdgcn_mfma_f32_16x16x32_bf16(af[m], bf[n], acc[m][n], 0, 0, 0);
    __syncthreads();
  }

  const int rr = (lane >> 4) * 4;
#pragma unroll
  for (int n = 0; n < 4; n++){
    int col = col0 + wc*64 + n*16 + fr;
    float bv = bias ? bias[col] : 0.f;
#pragma unroll
    for (int m = 0; m < 4; m++){
      int row = row0 + wr*64 + m*16 + rr;
#pragma unroll
      for (int r = 0; r < 4; r++){
        float v = acc[m][n][r] + bv;
        if (Cf) Cf[(size_t)(row + r) * N + col] = v;
        else    Cb[(size_t)(row + r) * N + col] = f2bf(v);
      }
    }
  }
}

// ---------------- RoPE (in-place on bf16 q and k; q also scaled by 1/sqrt(D)) ----------------
__global__ void rope_kernel(unsigned short* __restrict__ q, unsigned short* __restrict__ k,
                            const int* __restrict__ pos,
                            const float* __restrict__ cosT, const float* __restrict__ sinT)
{
  int idx = blockIdx.x * blockDim.x + threadIdx.x;
  const int qN = TOK * NH * 64;
  if (idx < qN){
    int d  = idx & 63;
    int hh = (idx >> 6) & (NH - 1);
    int t  = idx >> 10;
    int p  = pos[t & (Ss - 1)];
    float c = cosT[p * HD + d], s = sinT[p * HD + d];
    unsigned short* base = q + (size_t)t * HIDDEN + hh * HD;
    float lo = bf2f(base[d]), hi = bf2f(base[d + 64]);
    base[d]      = f2bf((lo * c - hi * s) * QSCALE);
    base[d + 64] = f2bf((hi * c + lo * s) * QSCALE);
  } else {
    int j  = idx - qN;
    int d  = j & 63;
    int hh = (j >> 6) & (NKV - 1);
    int t  = j >> 8;
    int p  = pos[t & (Ss - 1)];
    float c = cosT[p * HD + d], s = sinT[p * HD + d];
    unsigned short* base = k + (size_t)t * KVD + hh * HD;
    float lo = bf2f(base[d]), hi = bf2f(base[d + 64]);
    base[d]      = f2bf(lo * c - hi * s);
    base[d + 64] = f2bf(hi * c + lo * s);
  }
}

// ---------------- Flash attention (GQA, no causal mask, additive mask over k) ----------------
// grid: (qtile=16, head=16, batch=2); 256 threads = 4 waves; wave handles 32 q-rows.
__global__ __launch_bounds__(256) void attn_kernel(
    const unsigned short* __restrict__ Q,   // [TOK][HIDDEN] bf16, post-RoPE, pre-scaled
    const unsigned short* __restrict__ Kb,  // [TOK][KVD]
    const unsigned short* __restrict__ Vb,  // [TOK][KVD]
    const float* __restrict__ mask,         // [Bb][Ss]
    unsigned short* __restrict__ O)         // [TOK][HIDDEN] bf16
{
  __shared__ unsigned short Klds[64 * 136];       // K tile [64][128] padded to 136
  __shared__ unsigned short Vt[128 * 72];         // V^T tile [128][64] padded to 72
  __shared__ unsigned short Plds[4][32 * 72];     // per-wave P tile [32][64] padded

  const int tid = threadIdx.x, lane = tid & 63, wid = tid >> 6;
  const int qt = blockIdx.x, h = blockIdx.y, b = blockIdx.z;
  const int kvh = h >> 2;                          // GQA: repeat-interleave -> h/4
  const int tokQ = b * Ss + qt * 128 + wid * 32;
  const int fr  = lane & 15;
  const int fk8 = (lane >> 4) * 8;
  const int rr  = (lane >> 4) * 4;

  // Q fragments in registers: [2 row-frags][4 d-slices]
  short8 qf[2][4];
#pragma unroll
  for (int m = 0; m < 2; m++)
#pragma unroll
    for (int ks = 0; ks < 4; ks++)
      qf[m][ks] = *(const short8*)(Q + (size_t)(tokQ + m*16 + fr) * HIDDEN + h * HD + ks*32 + fk8);

  const f32x4 vzero = {0.f, 0.f, 0.f, 0.f};
  f32x4 oacc[2][8];
#pragma unroll
  for (int m = 0; m < 2; m++)
#pragma unroll
    for (int dn = 0; dn < 8; dn++) oacc[m][dn] = vzero;
  float mrow[2][4], lrow[2][4];
#pragma unroll
  for (int m = 0; m < 2; m++)
#pragma unroll
    for (int r = 0; r < 4; r++){ mrow[m][r] = -1e30f; lrow[m][r] = 0.f; }

  const size_t kvbase = (size_t)b * Ss * KVD + (size_t)kvh * HD;

  for (int kt = 0; kt < Ss / 64; kt++){
    const int ks0 = kt * 64;
    // stage K tile: coalesced 16B loads, padded LDS rows
#pragma unroll
    for (int i = 0; i < 4; i++){
      int c = tid + i * 256;
      int r = c >> 4, d0 = (c & 15) * 8;
      short8 v = *(const short8*)(Kb + kvbase + (size_t)(ks0 + r) * KVD + d0);
      *(short8*)&Klds[r * 136 + d0] = v;
    }
    // stage V^T tile: lane-per-row loads, scalar transposed LDS writes (conflict-free)
#pragma unroll
    for (int i = 0; i < 4; i++){
      int c = tid + i * 256;
      int kk = c & 63, d0 = (c >> 6) * 8;
      short8 v = *(const short8*)(Vb + kvbase + (size_t)(ks0 + kk) * KVD + d0);
#pragma unroll
      for (int j = 0; j < 8; j++) Vt[(d0 + j) * 72 + kk] = (unsigned short)v[j];
    }
    __syncthreads();

    // S = Q * K^T   [32 rows][64 cols] per wave
    f32x4 sf[2][4];
#pragma unroll
    for (int m = 0; m < 2; m++)
#pragma unroll
      for (int n = 0; n < 4; n++) sf[m][n] = vzero;
#pragma unroll
    for (int ks = 0; ks < 4; ks++){
      short8 kf[4];
#pragma unroll
      for (int n = 0; n < 4; n++) kf[n] = *(const short8*)&Klds[(n*16 + fr) * 136 + ks*32 + fk8];
#pragma unroll
      for (int m = 0; m < 2; m++)
#pragma unroll
        for (int n = 0; n < 4; n++)
          sf[m][n] = __builtin_amdgcn_mfma_f32_16x16x32_bf16(qf[m][ks], kf[n], sf[m][n], 0, 0, 0);
    }
    // additive attention mask (indexed by k position)
    float mk[4];
#pragma unroll
    for (int n = 0; n < 4; n++) mk[n] = mask[b * Ss + ks0 + n*16 + fr];
#pragma unroll
    for (int m = 0; m < 2; m++)
#pragma unroll
      for (int n = 0; n < 4; n++)
#pragma unroll
        for (int r = 0; r < 4; r++) sf[m][n][r] += mk[n];

    // online softmax, per row (row = (lane>>4)*4 + r within m-frag)
#pragma unroll
    for (int m = 0; m < 2; m++){
#pragma unroll
      for (int r = 0; r < 4; r++){
        float vmax = fmaxf(fmaxf(sf[m][0][r], sf[m][1][r]), fmaxf(sf[m][2][r], sf[m][3][r]));
#pragma unroll
        for (int off = 1; off < 16; off <<= 1) vmax = fmaxf(vmax, __shfl_xor(vmax, off, 64));
        float mnew = fmaxf(mrow[m][r], vmax);
        float sc = __expf(mrow[m][r] - mnew);
        mrow[m][r] = mnew;
        float rs = 0.f;
#pragma unroll
        for (int n = 0; n < 4; n++){
          float p = __expf(sf[m][n][r] - mnew);
          sf[m][n][r] = p;
          rs += p;
        }
#pragma unroll
        for (int off = 1; off < 16; off <<= 1) rs += __shfl_xor(rs, off, 64);
        lrow[m][r] = lrow[m][r] * sc + rs;
#pragma unroll
        for (int dn = 0; dn < 8; dn++) oacc[m][dn][r] *= sc;
      }
    }

    // P -> per-wave LDS (bf16), then reload as A-fragments for PV
    unsigned short* P = &Plds[wid][0];
#pragma unroll
    for (int m = 0; m < 2; m++)
#pragma unroll
      for (int n = 0; n < 4; n++)
#pragma unroll
        for (int r = 0; r < 4; r++)
          P[(m*16 + rr + r) * 72 + n*16 + fr] = f2bf(sf[m][n][r]);
    __threadfence_block();   // order P writes before P reads (same wave, fence for compiler)

    // O += P * V
#pragma unroll
    for (int ks2 = 0; ks2 < 2; ks2++){
      short8 pf[2];
#pragma unroll
      for (int m = 0; m < 2; m++) pf[m] = *(const short8*)&P[(m*16 + fr) * 72 + ks2*32 + fk8];
#pragma unroll
      for (int dn = 0; dn < 8; dn++){
        short8 vf = *(const short8*)&Vt[(dn*16 + fr) * 72 + ks2*32 + fk8];
#pragma unroll
        for (int m = 0; m < 2; m++)
          oacc[m][dn] = __builtin_amdgcn_mfma_f32_16x16x32_bf16(pf[m], vf, oacc[m][dn], 0, 0, 0);
      }
    }
    __syncthreads();
  }

  // epilogue: O /= l, store bf16
#pragma unroll
  for (int m = 0; m < 2; m++){
#pragma unroll
    for (int r = 0; r < 4; r++){
      float inv = 1.0f / lrow[m][r];
      int row = tokQ + m*16 + rr + r;
#pragma unroll
      for (int dn = 0; dn < 8; dn++)
        O[(size_t)row * HIDDEN + h * HD + dn*16 + fr] = f2bf(oacc[m][dn][r] * inv);
    }
  }
}

// ---------------- launcher ----------------
extern "C" void kernel_launch(void* const* d_in, const int* in_sizes, int n_in,
                              void* d_out, int out_size, void* d_ws, size_t ws_size,
                              hipStream_t stream)
{
  (void)in_sizes; (void)n_in; (void)out_size; (void)ws_size;
  const float* hs   = (const float*)d_in[0];
  const float* mask = (const float*)d_in[1];
  const int*   pos  = (const int*)d_in[2];
  const float* qw   = (const float*)d_in[3];
  const float* qb   = (const float*)d_in[4];
  const float* kw   = (const float*)d_in[5];
  const float* kb   = (const float*)d_in[6];
  const float* vw   = (const float*)d_in[7];
  const float* vb   = (const float*)d_in[8];
  const float* ow   = (const float*)d_in[9];
  const float* cosT = (const float*)d_in[10];
  const float* sinT = (const float*)d_in[11];
  float* out = (float*)d_out;

  unsigned short* ws  = (unsigned short*)d_ws;
  unsigned short* hsB = ws;                                   // [4096][2048]
  unsigned short* qwB = hsB + (size_t)TOK * HIDDEN;           // [2048][2048]
  unsigned short* kwB = qwB + (size_t)HIDDEN * HIDDEN;        // [512][2048]
  unsigned short* vwB = kwB + (size_t)KVD * HIDDEN;           // [512][2048]
  unsigned short* owB = vwB + (size_t)KVD * HIDDEN;           // [2048][2048]
  unsigned short* qB  = owB + (size_t)HIDDEN * HIDDEN;        // [4096][2048]
  unsigned short* kB  = qB  + (size_t)TOK * HIDDEN;           // [4096][512]
  unsigned short* vB  = kB  + (size_t)TOK * KVD;              // [4096][512]
  unsigned short* aoB = vB  + (size_t)TOK * KVD;              // [4096][2048]
  // total ws use: ~76 MB

  auto cvt = [&](const float* src, unsigned short* dst, size_t n){
    int n4 = (int)(n / 4);
    cvt_kernel<<<(n4 + 255) / 256, 256, 0, stream>>>(src, dst, n4);
  };
  cvt(hs, hsB, (size_t)TOK * HIDDEN);
  cvt(qw, qwB, (size_t)HIDDEN * HIDDEN);
  cvt(kw, kwB, (size_t)KVD * HIDDEN);
  cvt(vw, vwB, (size_t)KVD * HIDDEN);
  cvt(ow, owB, (size_t)HIDDEN * HIDDEN);

  // projections
  gemm_nt<<<dim3(TOK/128, HIDDEN/128), 256, 0, stream>>>(hsB, qwB, qb, qB, nullptr, TOK, HIDDEN, HIDDEN);
  gemm_nt<<<dim3(TOK/128, KVD/128),    256, 0, stream>>>(hsB, kwB, kb, kB, nullptr, TOK, KVD,    HIDDEN);
  gemm_nt<<<dim3(TOK/128, KVD/128),    256, 0, stream>>>(hsB, vwB, vb, vB, nullptr, TOK, KVD,    HIDDEN);

  // RoPE (q scaled by 1/sqrt(D))
  {
    int total = TOK * NH * 64 + TOK * NKV * 64;   // 5,242,880 -> exact multiple of 256
    rope_kernel<<<total / 256, 256, 0, stream>>>(qB, kB, pos, cosT, sinT);
  }

  // attention
  attn_kernel<<<dim3(Ss/128, NH, Bb), 256, 0, stream>>>(qB, kB, vB, mask, aoB);

  // output projection -> fp32 d_out
  gemm_nt<<<dim3(TOK/128, HIDDEN/128), 256, 0, stream>>>(aoB, owB, nullptr, nullptr, out, TOK, HIDDEN, HIDDEN);
}

// Round 6
// 379.601 us; speedup vs baseline: 1.2202x; 1.2202x over previous
//
#include <hip/hip_runtime.h>

#define HIDDEN 2048
#define NH 16
#define NKV 4
#define HD 128
#define Bb 2
#define Ss 2048
#define TOK 4096           // Bb*Ss
#define KVD 512            // NKV*HD
#define KVROW 1024         // combined K|V row stride
#define LOG2E 1.4426950408889634f
#define QSCALE (0.08838834764831845f * 1.4426950408889634f)   // log2e/sqrt(128)
#define DEFER 11.54f       // 8 nats in log2 units

typedef short short8 __attribute__((ext_vector_type(8)));
typedef float f32x4 __attribute__((ext_vector_type(4)));

#define AS1 __attribute__((address_space(1)))
#define AS3 __attribute__((address_space(3)))

__device__ __forceinline__ float exp2fast(float x){ return __builtin_amdgcn_exp2f(x); }

__device__ __forceinline__ float bf2f(unsigned short u){
  union { unsigned int i; float f; } x; x.i = ((unsigned int)u) << 16; return x.f;
}
__device__ __forceinline__ unsigned short f2bf(float f){
  union { float f; unsigned int i; } x; x.f = f;
  unsigned int r = x.i + 0x7FFFu + ((x.i >> 16) & 1u);   // RNE
  return (unsigned short)(r >> 16);
}
__device__ __forceinline__ void gld_lds16(const void* g, void* l){
  __builtin_amdgcn_global_load_lds((const AS1 void*)g, (AS3 void*)l, 16, 0, 0);
}

// ---------------- fused fp32 -> bf16 conversion of all 5 tensors ----------------
// ws prefix layout matches source order: hsB | qwB | kwB | vwB | owB (contiguous)
#define R0 2097152   // hs  f4 count
#define R1 3145728   // + qw
#define R2 3407872   // + kw
#define R3 3670016   // + vw
#define R4 4718592   // + ow (total)
__global__ void cvt_all(const float* __restrict__ s0, const float* __restrict__ s1,
                        const float* __restrict__ s2, const float* __restrict__ s3,
                        const float* __restrict__ s4, unsigned short* __restrict__ dst){
  int i = blockIdx.x * 256 + threadIdx.x;     // float4 index, grid exact
  const float* src; int off;
  if      (i < R0){ src = s0; off = 0;  }
  else if (i < R1){ src = s1; off = R0; }
  else if (i < R2){ src = s2; off = R1; }
  else if (i < R3){ src = s3; off = R2; }
  else            { src = s4; off = R3; }
  float4 v = reinterpret_cast<const float4*>(src)[i - off];
  ushort4 o;
  o.x = f2bf(v.x); o.y = f2bf(v.y); o.z = f2bf(v.z); o.w = f2bf(v.w);
  reinterpret_cast<ushort4*>(dst)[i] = o;
}

// ---------------- NT GEMM: C[M,N] = A[M,K] * B[N,K]^T (+bias) ----------------
__global__ __launch_bounds__(256) void gemm_nt(
    const unsigned short* __restrict__ A,
    const unsigned short* __restrict__ Bw,
    const float* __restrict__ bias,        // may be null
    const float* __restrict__ bias2,       // if non-null: used for col >= 512
    unsigned short* __restrict__ Cb,       // bf16 out (if Cf==null)
    float* __restrict__ Cf,                // f32 out (if non-null)
    int M, int N, int K)
{
  __shared__ unsigned short Alds[128*32];
  __shared__ unsigned short Blds[128*32];
  const int tid  = threadIdx.x;
  const int lane = tid & 63;
  const int wr = (tid >> 7) & 1;
  const int wc = (tid >> 6) & 1;
  const int row0 = blockIdx.x * 128;
  const int col0 = blockIdx.y * 128;

  const f32x4 vzero = {0.f, 0.f, 0.f, 0.f};
  f32x4 acc[4][4];
#pragma unroll
  for (int m = 0; m < 4; m++)
#pragma unroll
    for (int n = 0; n < 4; n++) acc[m][n] = vzero;

  const int c0 = tid, c1 = tid + 256;
  const int ra0 = c0 >> 2, ka0 = (c0 & 3) * 8;
  const int ra1 = c1 >> 2, ka1 = (c1 & 3) * 8;

  const int fr  = lane & 15;
  const int fk8 = (lane >> 4) * 8;

  for (int kt = 0; kt < K; kt += 32){
    gld_lds16(A  + (size_t)(row0 + ra0) * K + kt + ka0, &Alds[c0 * 8]);
    gld_lds16(A  + (size_t)(row0 + ra1) * K + kt + ka1, &Alds[c1 * 8]);
    gld_lds16(Bw + (size_t)(col0 + ra0) * K + kt + ka0, &Blds[c0 * 8]);
    gld_lds16(Bw + (size_t)(col0 + ra1) * K + kt + ka1, &Blds[c1 * 8]);
    __syncthreads();

    short8 af[4], bf[4];
#pragma unroll
    for (int m = 0; m < 4; m++) af[m] = *(const short8*)&Alds[(wr*64 + m*16 + fr)*32 + fk8];
#pragma unroll
    for (int n = 0; n < 4; n++) bf[n] = *(const short8*)&Blds[(wc*64 + n*16 + fr)*32 + fk8];
#pragma unroll
    for (int m = 0; m < 4; m++)
#pragma unroll
      for (int n = 0; n < 4; n++)
        acc[m][n] = __builtin_amdgcn_mfma_f32_16x16x32_bf16(af[m], bf[n], acc[m][n], 0, 0, 0);
    __syncthreads();
  }

  const int rr = (lane >> 4) * 4;
#pragma unroll
  for (int n = 0; n < 4; n++){
    int col = col0 + wc*64 + n*16 + fr;
    float bv = 0.f;
    if (bias) bv = (bias2 && col >= 512) ? bias2[col - 512] : bias[col];
#pragma unroll
    for (int m = 0; m < 4; m++){
      int row = row0 + wr*64 + m*16 + rr;
#pragma unroll
      for (int r = 0; r < 4; r++){
        float v = acc[m][n][r] + bv;
        if (Cf) Cf[(size_t)(row + r) * N + col] = v;
        else    Cb[(size_t)(row + r) * N + col] = f2bf(v);
      }
    }
  }
}

// ---------------- RoPE (in-place; q scaled by log2e/sqrt(D)) ----------------
__global__ void rope_kernel(unsigned short* __restrict__ q, unsigned short* __restrict__ kv,
                            const int* __restrict__ pos,
                            const float* __restrict__ cosT, const float* __restrict__ sinT)
{
  int idx = blockIdx.x * blockDim.x + threadIdx.x;
  const int qN = TOK * NH * 64;
  if (idx < qN){
    int d  = idx & 63;
    int hh = (idx >> 6) & (NH - 1);
    int t  = idx >> 10;
    int p  = pos[t & (Ss - 1)];
    float c = cosT[p * HD + d], s = sinT[p * HD + d];
    unsigned short* base = q + (size_t)t * HIDDEN + hh * HD;
    float lo = bf2f(base[d]), hi = bf2f(base[d + 64]);
    base[d]      = f2bf((lo * c - hi * s) * QSCALE);
    base[d + 64] = f2bf((hi * c + lo * s) * QSCALE);
  } else {
    int j  = idx - qN;
    int d  = j & 63;
    int hh = (j >> 6) & (NKV - 1);
    int t  = j >> 8;
    int p  = pos[t & (Ss - 1)];
    float c = cosT[p * HD + d], s = sinT[p * HD + d];
    unsigned short* base = kv + (size_t)t * KVROW + hh * HD;   // K region only
    float lo = bf2f(base[d]), hi = bf2f(base[d + 64]);
    base[d]      = f2bf(lo * c - hi * s);
    base[d + 64] = f2bf(hi * c + lo * s);
  }
}

// ---------------- Flash attention (GQA) ----------------
// grid: (qtile=32, head=16, batch=2) = 1024 blocks; 4 waves, wave = 16 q-rows.
// KV combined buffer: K at col [0,512), V at [512,1024), row stride KVROW.
__global__ __launch_bounds__(256, 3) void attn_kernel(
    const unsigned short* __restrict__ Q,    // [TOK][HIDDEN], post-RoPE, pre-scaled
    const unsigned short* __restrict__ KV,   // [TOK][KVROW]
    const float* __restrict__ mask,          // [Bb][Ss]
    unsigned short* __restrict__ O)          // [TOK][HIDDEN]
{
  __shared__ unsigned short Klds[64 * 136];     // [64][128] padded
  __shared__ unsigned short Vt[128 * 72];       // V^T [128][64] padded
  __shared__ unsigned short Plds[4][16 * 72];   // per-wave P [16][64] padded, XOR-swizzled

  const int tid = threadIdx.x, lane = tid & 63, wid = tid >> 6;
  const int qt = blockIdx.x, h = blockIdx.y, b = blockIdx.z;
  const int kvh = h >> 2;
  const int tokQ = b * Ss + qt * 64 + wid * 16;
  const int fr  = lane & 15;
  const int g16 = lane >> 4;          // 0..3
  const int fk8 = g16 * 8;
  const int rr  = g16 * 4;

  short8 qf[4];
#pragma unroll
  for (int ks = 0; ks < 4; ks++)
    qf[ks] = *(const short8*)(Q + (size_t)(tokQ + fr) * HIDDEN + h * HD + ks*32 + fk8);

  const f32x4 vzero = {0.f, 0.f, 0.f, 0.f};
  f32x4 oacc[8];
#pragma unroll
  for (int dn = 0; dn < 8; dn++) oacc[dn] = vzero;
  float mrow[4], lrow[4];
#pragma unroll
  for (int r = 0; r < 4; r++){ mrow[r] = -1e30f; lrow[r] = 0.f; }

  const size_t kvbK = (size_t)b * Ss * KVROW + (size_t)kvh * HD;
  const size_t kvbV = kvbK + 512;

  // staging chunk geometry (per thread, 4 chunks of 8 bf16)
  short8 kpre[4], vpre[4];
#pragma unroll
  for (int i = 0; i < 4; i++){
    int c = tid + i * 256;
    int rK = c >> 4, dK = (c & 15) * 8;
    kpre[i] = *(const short8*)(KV + kvbK + (size_t)rK * KVROW + dK);
    int kk = c & 63, dV = (c >> 6) * 8;
    vpre[i] = *(const short8*)(KV + kvbV + (size_t)kk * KVROW + dV);
  }

  for (int kt = 0; kt < Ss / 64; kt++){
    if (kt) __syncthreads();
    // write prefetched tile to LDS
#pragma unroll
    for (int i = 0; i < 4; i++){
      int c = tid + i * 256;
      int rK = c >> 4, dK = (c & 15) * 8;
      *(short8*)&Klds[rK * 136 + dK] = kpre[i];
      int kk = c & 63, dV = (c >> 6) * 8;
#pragma unroll
      for (int j = 0; j < 8; j++) Vt[(dV + j) * 72 + kk] = (unsigned short)vpre[i][j];
    }
    __syncthreads();
    // prefetch next tile into regs (hides under compute below)
    if (kt + 1 < Ss / 64){
      const int ks0n = (kt + 1) * 64;
#pragma unroll
      for (int i = 0; i < 4; i++){
        int c = tid + i * 256;
        int rK = c >> 4, dK = (c & 15) * 8;
        kpre[i] = *(const short8*)(KV + kvbK + (size_t)(ks0n + rK) * KVROW + dK);
        int kk = c & 63, dV = (c >> 6) * 8;
        vpre[i] = *(const short8*)(KV + kvbV + (size_t)(ks0n + kk) * KVROW + dV);
      }
    }

    // S = Q K^T  [16 rows][64 cols] per wave
    f32x4 sf[4];
#pragma unroll
    for (int n = 0; n < 4; n++) sf[n] = vzero;
    __builtin_amdgcn_s_setprio(1);
#pragma unroll
    for (int ks = 0; ks < 4; ks++){
      short8 kf[4];
#pragma unroll
      for (int n = 0; n < 4; n++) kf[n] = *(const short8*)&Klds[(n*16 + fr) * 136 + ks*32 + fk8];
#pragma unroll
      for (int n = 0; n < 4; n++)
        sf[n] = __builtin_amdgcn_mfma_f32_16x16x32_bf16(qf[ks], kf[n], sf[n], 0, 0, 0);
    }
    __builtin_amdgcn_s_setprio(0);

    // mask (log2 domain)
    float mk[4];
#pragma unroll
    for (int n = 0; n < 4; n++) mk[n] = mask[b * Ss + kt*64 + n*16 + fr] * LOG2E;
#pragma unroll
    for (int n = 0; n < 4; n++)
#pragma unroll
      for (int r = 0; r < 4; r++) sf[n][r] += mk[n];

    // online softmax with defer-max (log2 domain)
    float vmax[4];
#pragma unroll
    for (int r = 0; r < 4; r++){
      float vm = fmaxf(fmaxf(sf[0][r], sf[1][r]), fmaxf(sf[2][r], sf[3][r]));
#pragma unroll
      for (int off = 1; off < 16; off <<= 1) vm = fmaxf(vm, __shfl_xor(vm, off, 64));
      vmax[r] = vm;
    }
    bool need = false;
#pragma unroll
    for (int r = 0; r < 4; r++) need |= (vmax[r] > mrow[r] + DEFER);
    if (__any(need)){
#pragma unroll
      for (int r = 0; r < 4; r++){
        float mnew = fmaxf(mrow[r], vmax[r]);
        float sc = exp2fast(mrow[r] - mnew);
        mrow[r] = mnew; lrow[r] *= sc;
#pragma unroll
        for (int dn = 0; dn < 8; dn++) oacc[dn][r] *= sc;
      }
    }
#pragma unroll
    for (int r = 0; r < 4; r++){
      float rs = 0.f;
#pragma unroll
      for (int n = 0; n < 4; n++){
        float p = exp2fast(sf[n][r] - mrow[r]);
        sf[n][r] = p;
        rs += p;
      }
#pragma unroll
      for (int off = 1; off < 16; off <<= 1) rs += __shfl_xor(rs, off, 64);
      lrow[r] += rs;
    }

    // P -> per-wave LDS (bf16), XOR-swizzled: phys_col = col ^ (((row>>2)&3)<<4)
    unsigned short* P = &Plds[wid][0];
#pragma unroll
    for (int n = 0; n < 4; n++){
      int csw = ((n ^ g16) * 16) + fr;          // row group = g16 for all 4 r
#pragma unroll
      for (int r = 0; r < 4; r++)
        P[(rr + r) * 72 + csw] = f2bf(sf[n][r]);
    }
    __threadfence_block();

    // O += P * V
    __builtin_amdgcn_s_setprio(1);
#pragma unroll
    for (int ks2 = 0; ks2 < 2; ks2++){
      int csw = (ks2*32 + fk8) ^ (((fr >> 2) & 3) << 4);
      short8 pf = *(const short8*)&P[fr * 72 + csw];
#pragma unroll
      for (int dn = 0; dn < 8; dn++){
        short8 vf = *(const short8*)&Vt[(dn*16 + fr) * 72 + ks2*32 + fk8];
        oacc[dn] = __builtin_amdgcn_mfma_f32_16x16x32_bf16(pf, vf, oacc[dn], 0, 0, 0);
      }
    }
    __builtin_amdgcn_s_setprio(0);
  }

  // epilogue
#pragma unroll
  for (int r = 0; r < 4; r++){
    float inv = 1.0f / lrow[r];
    int row = tokQ + rr + r;
#pragma unroll
    for (int dn = 0; dn < 8; dn++)
      O[(size_t)row * HIDDEN + h * HD + dn*16 + fr] = f2bf(oacc[dn][r] * inv);
  }
}

// ---------------- launcher ----------------
extern "C" void kernel_launch(void* const* d_in, const int* in_sizes, int n_in,
                              void* d_out, int out_size, void* d_ws, size_t ws_size,
                              hipStream_t stream)
{
  (void)in_sizes; (void)n_in; (void)out_size; (void)ws_size;
  const float* hs   = (const float*)d_in[0];
  const float* mask = (const float*)d_in[1];
  const int*   pos  = (const int*)d_in[2];
  const float* qw   = (const float*)d_in[3];
  const float* qb   = (const float*)d_in[4];
  const float* kw   = (const float*)d_in[5];
  const float* kb   = (const float*)d_in[6];
  const float* vw   = (const float*)d_in[7];
  const float* vb   = (const float*)d_in[8];
  const float* ow   = (const float*)d_in[9];
  const float* cosT = (const float*)d_in[10];
  const float* sinT = (const float*)d_in[11];
  float* out = (float*)d_out;

  unsigned short* ws  = (unsigned short*)d_ws;
  unsigned short* hsB = ws;                                   // [4096][2048]
  unsigned short* qwB = hsB + (size_t)TOK * HIDDEN;           // [2048][2048]
  unsigned short* kwB = qwB + (size_t)HIDDEN * HIDDEN;        // [512][2048]
  unsigned short* vwB = kwB + (size_t)KVD * HIDDEN;           // [512][2048] (contiguous with kwB)
  unsigned short* owB = vwB + (size_t)KVD * HIDDEN;           // [2048][2048]
  unsigned short* qB  = owB + (size_t)HIDDEN * HIDDEN;        // [4096][2048]
  unsigned short* kvB = qB  + (size_t)TOK * HIDDEN;           // [4096][1024]  K|V combined
  unsigned short* aoB = kvB + (size_t)TOK * KVROW;            // [4096][2048]
  (void)vwB;

  // one fused conversion pass (dst = ws prefix, contiguous & in order)
  cvt_all<<<R4 / 256, 256, 0, stream>>>(hs, qw, kw, vw, ow, ws);

  // projections: Q (N=2048) and combined K|V (N=1024)
  gemm_nt<<<dim3(TOK/128, HIDDEN/128), 256, 0, stream>>>(hsB, qwB, qb, nullptr, qB, nullptr, TOK, HIDDEN, HIDDEN);
  gemm_nt<<<dim3(TOK/128, KVROW/128),  256, 0, stream>>>(hsB, kwB, kb, vb, kvB, nullptr, TOK, KVROW, HIDDEN);

  // RoPE
  {
    int total = TOK * NH * 64 + TOK * NKV * 64;
    rope_kernel<<<total / 256, 256, 0, stream>>>(qB, kvB, pos, cosT, sinT);
  }

  // attention
  attn_kernel<<<dim3(Ss/64, NH, Bb), 256, 0, stream>>>(qB, kvB, mask, aoB);

  // output projection -> fp32 d_out
  gemm_nt<<<dim3(TOK/128, HIDDEN/128), 256, 0, stream>>>(aoB, owB, nullptr, nullptr, nullptr, out, TOK, HIDDEN, HIDDEN);
}